// Round 4
// baseline (88.353 us; speedup 1.0000x reference)
//
#include <hip/hip_runtime.h>
#include <hip/hip_bf16.h>
#include <stdint.h>
#include <math.h>

#define NB 8
#define NT 2048
#define NC 1024
#define NH 64

typedef __attribute__((ext_vector_type(8))) short bf16x8;
typedef __attribute__((ext_vector_type(4))) float f32x4;

#define MFMA(a, b, c) __builtin_amdgcn_mfma_f32_16x16x32_bf16((a), (b), (c), 0, 0, 0)

static __device__ __forceinline__ short f2bf(float f) {
  union { float f; uint32_t u; } v; v.f = f;
  uint32_t r = v.u + 0x7FFFu + ((v.u >> 16) & 1u);  // RNE bf16
  return (short)(r >> 16);
}
static __device__ __forceinline__ float bf2f(short h) {
  union { uint32_t u; float f; } v; v.u = ((uint32_t)(uint16_t)h) << 16;
  return v.f;
}
static __device__ __forceinline__ void gload_lds16(const void* g, void* l) {
  __builtin_amdgcn_global_load_lds(
      (const __attribute__((address_space(1))) uint32_t*)g,
      (__attribute__((address_space(3))) uint32_t*)l, 16, 0, 0);
}

// ---------------------------------------------------------------------------
// Kernel 0: build Wt[192][1024] bf16 = concat(Wq^T * 0.125, Wk^T, Wv^T)
// ---------------------------------------------------------------------------
__global__ __launch_bounds__(256) void w_prep(const float* __restrict__ Wq,
                                              const float* __restrict__ Wk,
                                              const float* __restrict__ Wv,
                                              short* __restrict__ Wt) {
  __shared__ short tile[64][68];
  const int blk = blockIdx.x;          // 48 blocks: 3 mats x 16 k-tiles
  const int mat = blk / 16;
  const int k0 = (blk % 16) * 64;
  const float* W = (mat == 0) ? Wq : (mat == 1) ? Wk : Wv;
  const float scale = (mat == 0) ? 0.125f : 1.0f;
  const int tid = threadIdx.x;
  {
    int kk = tid >> 2;
    int h0 = (tid & 3) * 16;
    const float* src = W + (size_t)(k0 + kk) * NH + h0;
#pragma unroll
    for (int i = 0; i < 16; ++i) tile[kk][h0 + i] = f2bf(src[i] * scale);
  }
  __syncthreads();
  {
    int j = tid >> 2;
    int kk0 = (tid & 3) * 16;
    bf16x8 t0, t1;
#pragma unroll
    for (int i = 0; i < 8; ++i) { t0[i] = tile[kk0 + i][j]; t1[i] = tile[kk0 + 8 + i][j]; }
    short* dst = Wt + (size_t)(mat * 64 + j) * NC + k0 + kk0;
    *(bf16x8*)dst = t0;
    *(bf16x8*)(dst + 8) = t1;
  }
}

// ---------------------------------------------------------------------------
// Kernel 1: QKV projection v4. 256 blocks x 64 rows, K-step 64, double-buffer.
// Per wave: 16 rows x 192 cols = 12 frags; 24 MFMA / K-step.
// LDS/buf: xs 64x64 fp32 (16KB) + wt 192x64 bf16 (24KB) = 40KB; x2 = 80KB.
// V written TRANSPOSED: VTo[(b*64+h)][t].
// ---------------------------------------------------------------------------
__global__ __launch_bounds__(256) void qkv_proj(const float* __restrict__ x,
                                                const short* __restrict__ Wt,
                                                short* __restrict__ Qo,
                                                short* __restrict__ Ko,
                                                short* __restrict__ VTo) {
  __shared__ char lds_raw[2][40960];
  const int tid = threadIdx.x;
  const int lane = tid & 63;
  const int wave = tid >> 6;
  const int l15 = lane & 15;
  const int hi = lane >> 4;
  const int m0 = blockIdx.x * 64;

  f32x4 acc[12];
#pragma unroll
  for (int f = 0; f < 12; ++f) acc[f] = (f32x4){0.f, 0.f, 0.f, 0.f};

  // staging source coords (pre-swizzled so linear LDS dest + swizzled read match)
  int xrow[4], xcol[4], wrow[6], wcol[6];
#pragma unroll
  for (int i = 0; i < 4; ++i) {
    int off = i * 4096 + tid * 16;
    int ol = off ^ (((off >> 8) & 7) << 4);
    xrow[i] = ol >> 8; xcol[i] = (ol & 255) >> 2;
  }
#pragma unroll
  for (int i = 0; i < 6; ++i) {
    int off = i * 4096 + tid * 16;
    int ol = off ^ (((off >> 7) & 7) << 4);
    wrow[i] = ol >> 7; wcol[i] = (ol & 127) >> 1;
  }

#define STAGE(k0, buf)                                                          \
  {                                                                             \
    char* xsb_ = lds_raw[buf];                                                  \
    char* wtb_ = lds_raw[buf] + 16384;                                          \
    _Pragma("unroll")                                                           \
    for (int i = 0; i < 4; ++i)                                                 \
      gload_lds16(x + (size_t)(m0 + xrow[i]) * NC + (k0) + xcol[i],             \
                  xsb_ + i * 4096 + wave * 1024);                               \
    _Pragma("unroll")                                                           \
    for (int i = 0; i < 6; ++i)                                                 \
      gload_lds16(Wt + (size_t)wrow[i] * NC + (k0) + wcol[i],                   \
                  wtb_ + i * 4096 + wave * 1024);                               \
  }

  STAGE(0, 0);
  __syncthreads();
  int cur = 0;
  for (int t = 0; t < 16; ++t) {
    if (t + 1 < 16) STAGE((t + 1) * 64, cur ^ 1);
    const char* xsb = lds_raw[cur];
    const char* wtb = lds_raw[cur] + 16384;
    const int row = wave * 16 + l15;
#pragma unroll
    for (int s = 0; s < 2; ++s) {
      int o1 = (row * 256 + s * 128 + hi * 32) ^ ((row & 7) << 4);
      int o2 = (row * 256 + s * 128 + hi * 32 + 16) ^ ((row & 7) << 4);
      float4 q0 = *(const float4*)(xsb + o1);
      float4 q1 = *(const float4*)(xsb + o2);
      bf16x8 a;
      a[0] = f2bf(q0.x); a[1] = f2bf(q0.y); a[2] = f2bf(q0.z); a[3] = f2bf(q0.w);
      a[4] = f2bf(q1.x); a[5] = f2bf(q1.y); a[6] = f2bf(q1.z); a[7] = f2bf(q1.w);
#pragma unroll
      for (int f = 0; f < 12; ++f) {
        int c = f * 16 + l15;
        int ob = (c * 128 + s * 64 + hi * 16) ^ ((c & 7) << 4);
        bf16x8 b = *(const bf16x8*)(wtb + ob);
        acc[f] = MFMA(a, b, acc[f]);
      }
    }
    __syncthreads();
    cur ^= 1;
  }
#undef STAGE

  // epilogue: Q,K row-major [t][h]; V transposed [(b*64+h)][t]
#pragma unroll
  for (int f = 0; f < 12; ++f) {
    int c = f * 16 + l15;                 // global col 0..191
    int mat = c >> 6, h = c & 63;
    if (mat < 2) {
      short* dst = (mat == 0) ? Qo : Ko;
#pragma unroll
      for (int r = 0; r < 4; ++r) {
        int t = m0 + wave * 16 + hi * 4 + r;
        dst[(size_t)t * NH + h] = f2bf(acc[f][r]);
      }
    } else {
      int bb = m0 >> 11;
      int t0 = (m0 & 2047) + wave * 16 + hi * 4;
      short4 v;
      v.x = f2bf(acc[f][0]); v.y = f2bf(acc[f][1]);
      v.z = f2bf(acc[f][2]); v.w = f2bf(acc[f][3]);
      *(short4*)(VTo + ((size_t)(bb * 64 + h)) * NT + t0) = v;
    }
  }
}

// ---------------------------------------------------------------------------
// Kernel 2a: attention partial v4 — ONE key-tile per block, straight-line.
// Grid = 8 * 528 = 4224 uniform blocks. slot == blockIdx.x.
// One-shot softmax per tile (no online rescale needed).
// ---------------------------------------------------------------------------
__global__ __launch_bounds__(256) void attn_partial(const short* __restrict__ Q,
                                                    const short* __restrict__ K,
                                                    const short* __restrict__ Vt,
                                                    short* __restrict__ Op,
                                                    float2* __restrict__ ml) {
  __shared__ short Ps[4][16][72];
  const int tid = threadIdx.x;
  const int lane = tid & 63;
  const int wave = tid >> 6;
  const int l15 = lane & 15;
  const int hi = lane >> 4;
  const int kgrp = hi * 8;

  const int bid = blockIdx.x;
  const int b = bid / 528;
  const int r5 = bid % 528;
  int qt = (int)((sqrtf(8.0f * (float)r5 + 1.0f) - 1.0f) * 0.5f);
  while ((qt + 1) * (qt + 2) / 2 <= r5) ++qt;
  while (qt * (qt + 1) / 2 > r5) --qt;
  const int kt = r5 - qt * (qt + 1) / 2;

  const size_t qbase = ((size_t)b * NT + qt * 64 + wave * 16 + l15) * NH;
  const bf16x8 qf0 = *(const bf16x8*)(Q + qbase + kgrp);
  const bf16x8 qf1 = *(const bf16x8*)(Q + qbase + 32 + kgrp);

  const short* kb = K + ((size_t)b * NT + kt * 64) * NH;
  bf16x8 kf[4][2];
#pragma unroll
  for (int f = 0; f < 4; ++f)
#pragma unroll
    for (int s = 0; s < 2; ++s)
      kf[f][s] = *(const bf16x8*)(kb + (f * 16 + l15) * NH + s * 32 + kgrp);
  bf16x8 vf[4][2];
#pragma unroll
  for (int f = 0; f < 4; ++f)
#pragma unroll
    for (int s = 0; s < 2; ++s)
      vf[f][s] = *(const bf16x8*)(Vt + ((size_t)(b * 64 + f * 16 + l15)) * NT +
                                  kt * 64 + s * 32 + kgrp);

  f32x4 s4[4];
#pragma unroll
  for (int f = 0; f < 4; ++f) {
    s4[f] = (f32x4){0.f, 0.f, 0.f, 0.f};
    s4[f] = MFMA(qf0, kf[f][0], s4[f]);
    s4[f] = MFMA(qf1, kf[f][1], s4[f]);
  }
  if (kt == qt) {                        // causal mask on the diagonal tile
#pragma unroll
    for (int f = 0; f < 4; ++f)
#pragma unroll
      for (int r = 0; r < 4; ++r)
        if (f * 16 + l15 > wave * 16 + hi * 4 + r) s4[f][r] = -INFINITY;
  }
  // one-shot softmax stats: row r at (hi*4+r), cols spread over l15 lanes
  float mt[4];
#pragma unroll
  for (int r = 0; r < 4; ++r)
    mt[r] = fmaxf(fmaxf(s4[0][r], s4[1][r]), fmaxf(s4[2][r], s4[3][r]));
#pragma unroll
  for (int d = 1; d < 16; d <<= 1)
#pragma unroll
    for (int r = 0; r < 4; ++r) mt[r] = fmaxf(mt[r], __shfl_xor(mt[r], d));
  float rs[4];
#pragma unroll
  for (int r = 0; r < 4; ++r) rs[r] = 0.f;
#pragma unroll
  for (int f = 0; f < 4; ++f)
#pragma unroll
    for (int r = 0; r < 4; ++r) {
      float p = __expf(s4[f][r] - mt[r]);
      s4[f][r] = p;
      rs[r] += p;
    }
#pragma unroll
  for (int d = 1; d < 16; d <<= 1)
#pragma unroll
    for (int r = 0; r < 4; ++r) rs[r] += __shfl_xor(rs[r], d);

  // P transpose through per-wave LDS (wave-internal, no barrier)
#pragma unroll
  for (int f = 0; f < 4; ++f)
#pragma unroll
    for (int r = 0; r < 4; ++r)
      Ps[wave][hi * 4 + r][f * 16 + l15] = f2bf(s4[f][r]);

  bf16x8 pa0 = *(const bf16x8*)&Ps[wave][l15][kgrp];
  bf16x8 pa1 = *(const bf16x8*)&Ps[wave][l15][32 + kgrp];
  f32x4 oacc[4];
#pragma unroll
  for (int f = 0; f < 4; ++f) {
    oacc[f] = (f32x4){0.f, 0.f, 0.f, 0.f};
    oacc[f] = MFMA(pa0, vf[f][0], oacc[f]);
    oacc[f] = MFMA(pa1, vf[f][1], oacc[f]);
  }
  // epilogue: unnormalized partial O (bf16) + per-row (m, l); slot == bid
  short* op = Op + ((size_t)bid << 12);
#pragma unroll
  for (int f = 0; f < 4; ++f)
#pragma unroll
    for (int r = 0; r < 4; ++r)
      op[(wave * 16 + hi * 4 + r) * 64 + f * 16 + l15] = f2bf(oacc[f][r]);
  if (l15 == 0) {
#pragma unroll
    for (int r = 0; r < 4; ++r) {
      int row = wave * 16 + hi * 4 + r;
      ml[(size_t)bid * 64 + row] = make_float2(mt[r], rs[r]);
    }
  }
}

// ---------------------------------------------------------------------------
// Kernel 2b: combine partials. 256 blocks (b,qt) x 512 threads.
// Chunks for (b,qt): slot0 = b*528 + qt*(qt+1)/2, count qt+1 (<=32).
// Thread: row r = tid>>3 (64 rows), h0 = (tid&7)*8.
// ---------------------------------------------------------------------------
__global__ __launch_bounds__(512) void attn_combine(const short* __restrict__ Op,
                                                    const float2* __restrict__ ml,
                                                    float* __restrict__ out) {
  const int bid = blockIdx.x;
  const int b = bid >> 5;
  const int qt = bid & 31;
  const int nch = qt + 1;
  const int slot0 = b * 528 + qt * (qt + 1) / 2;
  const int tid = threadIdx.x;
  const int r = tid >> 3;
  const int h0 = (tid & 7) * 8;

  float M = -INFINITY;
#pragma unroll 4
  for (int i = 0; i < nch; ++i)
    M = fmaxf(M, ml[(size_t)(slot0 + i) * 64 + r].x);

  float L = 0.f;
  float o[8];
#pragma unroll
  for (int j = 0; j < 8; ++j) o[j] = 0.f;
#pragma unroll 4
  for (int i = 0; i < nch; ++i) {
    float2 t = ml[(size_t)(slot0 + i) * 64 + r];
    float w = __expf(t.x - M);
    L += w * t.y;
    bf16x8 v = *(const bf16x8*)(Op + (((size_t)(slot0 + i)) << 12) + r * 64 + h0);
#pragma unroll
    for (int j = 0; j < 8; ++j) o[j] += w * bf2f(v[j]);
  }
  float inv = 1.f / L;
  float* po = out + (((size_t)b * NT) + qt * 64 + r) * NH + h0;
  float4 v0 = {o[0] * inv, o[1] * inv, o[2] * inv, o[3] * inv};
  float4 v1 = {o[4] * inv, o[5] * inv, o[6] * inv, o[7] * inv};
  *(float4*)po = v0;
  *(float4*)(po + 4) = v1;
}

// ---------------------------------------------------------------------------
extern "C" void kernel_launch(void* const* d_in, const int* in_sizes, int n_in,
                              void* d_out, int out_size, void* d_ws, size_t ws_size,
                              hipStream_t stream) {
  const float* x  = (const float*)d_in[0];
  const float* Wq = (const float*)d_in[1];
  const float* Wk = (const float*)d_in[2];
  const float* Wv = (const float*)d_in[3];
  float* out = (float*)d_out;

  char* ws = (char*)d_ws;
  short* Wt = (short*)ws;                          // 384 KB
  short* Qb = (short*)(ws + (size_t)(1 << 20));    // 2 MB
  short* Kb = (short*)(ws + (size_t)(3 << 20));    // 2 MB
  short* Vt = (short*)(ws + (size_t)(5 << 20));    // 2 MB (transposed V)
  short* Op = (short*)(ws + (size_t)(8 << 20));    // 4224 * 8KB = 33 MB
  float2* ml = (float2*)(ws + (size_t)(48 << 20)); // 2.2 MB

  hipLaunchKernelGGL(w_prep, dim3(48), dim3(256), 0, stream, Wq, Wk, Wv, Wt);
  hipLaunchKernelGGL(qkv_proj, dim3(256), dim3(256), 0, stream, x, Wt, Qb, Kb, Vt);
  hipLaunchKernelGGL(attn_partial, dim3(8 * 528), dim3(256), 0, stream, Qb, Kb, Vt, Op, ml);
  hipLaunchKernelGGL(attn_combine, dim3(256), dim3(512), 0, stream, Op, ml, out);
}

// Round 5
// 60.030 us; speedup vs baseline: 1.4718x; 1.4718x over previous
//
#include <hip/hip_runtime.h>
#include <hip/hip_bf16.h>
#include <stdint.h>

#define NB 8
#define NT 2048
#define NC 1024
#define NH 64

typedef __attribute__((ext_vector_type(8))) short bf16x8;
typedef __attribute__((ext_vector_type(4))) float f32x4;

#define MFMA(a, b, c) __builtin_amdgcn_mfma_f32_16x16x32_bf16((a), (b), (c), 0, 0, 0)

static __device__ __forceinline__ short f2bf(float f) {
  union { float f; uint32_t u; } v; v.f = f;
  uint32_t r = v.u + 0x7FFFu + ((v.u >> 16) & 1u);  // RNE bf16
  return (short)(r >> 16);
}
static __device__ __forceinline__ float bf2f(short h) {
  union { uint32_t u; float f; } v; v.u = ((uint32_t)(uint16_t)h) << 16;
  return v.f;
}
static __device__ __forceinline__ void gload_lds16(const void* g, void* l) {
  __builtin_amdgcn_global_load_lds(
      (const __attribute__((address_space(1))) uint32_t*)g,
      (__attribute__((address_space(3))) uint32_t*)l, 16, 0, 0);
}

// ---------------------------------------------------------------------------
// Kernel 0: build Wt[192][1024] bf16 = concat(Wq^T * 0.125, Wk^T, Wv^T)
// ---------------------------------------------------------------------------
__global__ __launch_bounds__(256) void w_prep(const float* __restrict__ Wq,
                                              const float* __restrict__ Wk,
                                              const float* __restrict__ Wv,
                                              short* __restrict__ Wt) {
  __shared__ short tile[64][68];
  const int blk = blockIdx.x;          // 48 blocks: 3 mats x 16 k-tiles
  const int mat = blk / 16;
  const int k0 = (blk % 16) * 64;
  const float* W = (mat == 0) ? Wq : (mat == 1) ? Wk : Wv;
  const float scale = (mat == 0) ? 0.125f : 1.0f;
  const int tid = threadIdx.x;
  {
    int kk = tid >> 2;
    int h0 = (tid & 3) * 16;
    const float* src = W + (size_t)(k0 + kk) * NH + h0;
#pragma unroll
    for (int i = 0; i < 16; ++i) tile[kk][h0 + i] = f2bf(src[i] * scale);
  }
  __syncthreads();
  {
    int j = tid >> 2;
    int kk0 = (tid & 3) * 16;
    bf16x8 t0, t1;
#pragma unroll
    for (int i = 0; i < 8; ++i) { t0[i] = tile[kk0 + i][j]; t1[i] = tile[kk0 + 8 + i][j]; }
    short* dst = Wt + (size_t)(mat * 64 + j) * NC + k0 + kk0;
    *(bf16x8*)dst = t0;
    *(bf16x8*)(dst + 8) = t1;
  }
}

// ---------------------------------------------------------------------------
// Kernel 1: QKV projection (R3-proven). 512 blocks x 32 rows, K-step 64,
// double-buffered global_load_lds w16, XOR-swizzled source addressing.
// V written TRANSPOSED: VTo[(b*64+h)][t].
// ---------------------------------------------------------------------------
__global__ __launch_bounds__(256) void qkv_proj(const float* __restrict__ x,
                                                const short* __restrict__ Wt,
                                                short* __restrict__ Qo,
                                                short* __restrict__ Ko,
                                                short* __restrict__ VTo) {
  __shared__ char lds_raw[2][32768];
  const int tid = threadIdx.x;
  const int lane = tid & 63;
  const int wave = tid >> 6;
  const int l15 = lane & 15;
  const int hi = lane >> 4;
  const int m0 = blockIdx.x * 32;
  const int mr = (wave & 1) * 16;        // wave's row group
  const int ncol = (wave >> 1) * 96;     // wave's col group (6 frags)

  f32x4 acc[6];
#pragma unroll
  for (int f = 0; f < 6; ++f) acc[f] = (f32x4){0.f, 0.f, 0.f, 0.f};

  int xrow[2], xcol[2], wrow[6], wcol[6];
#pragma unroll
  for (int i = 0; i < 2; ++i) {
    int off = wave * 2048 + i * 1024 + lane * 16;
    int ol = off ^ (((off >> 8) & 7) << 4);
    xrow[i] = ol >> 8; xcol[i] = (ol >> 2) & 63;
  }
#pragma unroll
  for (int i = 0; i < 6; ++i) {
    int off = wave * 6144 + i * 1024 + lane * 16;
    int ol = off ^ (((off >> 7) & 7) << 4);
    wrow[i] = ol >> 7; wcol[i] = (ol >> 1) & 63;
  }

#define STAGE(k0, buf)                                                          \
  {                                                                             \
    char* xsb_ = lds_raw[buf];                                                  \
    char* wtb_ = lds_raw[buf] + 8192;                                           \
    _Pragma("unroll")                                                           \
    for (int i = 0; i < 2; ++i)                                                 \
      gload_lds16(x + (size_t)(m0 + xrow[i]) * NC + (k0) + xcol[i],             \
                  xsb_ + wave * 2048 + i * 1024);                               \
    _Pragma("unroll")                                                           \
    for (int i = 0; i < 6; ++i)                                                 \
      gload_lds16(Wt + (size_t)wrow[i] * NC + (k0) + wcol[i],                   \
                  wtb_ + wave * 6144 + i * 1024);                               \
  }

  STAGE(0, 0);
  __syncthreads();
  int cur = 0;
  for (int t = 0; t < 16; ++t) {
    if (t + 1 < 16) STAGE((t + 1) * 64, cur ^ 1);
    const char* xsb = lds_raw[cur];
    const char* wtb = lds_raw[cur] + 8192;
#pragma unroll
    for (int s = 0; s < 2; ++s) {
      int r = mr + l15;
      int o1 = (r * 256 + s * 128 + hi * 32) ^ ((r & 7) << 4);
      int o2 = (r * 256 + s * 128 + hi * 32 + 16) ^ ((r & 7) << 4);
      float4 q0 = *(const float4*)(xsb + o1);
      float4 q1 = *(const float4*)(xsb + o2);
      bf16x8 a;
      a[0] = f2bf(q0.x); a[1] = f2bf(q0.y); a[2] = f2bf(q0.z); a[3] = f2bf(q0.w);
      a[4] = f2bf(q1.x); a[5] = f2bf(q1.y); a[6] = f2bf(q1.z); a[7] = f2bf(q1.w);
#pragma unroll
      for (int f = 0; f < 6; ++f) {
        int c = ncol + f * 16 + l15;
        int ob = (c * 128 + s * 64 + hi * 16) ^ ((c & 7) << 4);
        bf16x8 b = *(const bf16x8*)(wtb + ob);
        acc[f] = MFMA(a, b, acc[f]);
      }
    }
    __syncthreads();
    cur ^= 1;
  }
#undef STAGE

#pragma unroll
  for (int f = 0; f < 6; ++f) {
    int g = ncol + f * 16 + l15;          // global col 0..191
    int mat = g >> 6, h = g & 63;
    if (mat < 2) {
      short* dst = (mat == 0) ? Qo : Ko;
#pragma unroll
      for (int r = 0; r < 4; ++r) {
        int t = m0 + mr + hi * 4 + r;
        dst[(size_t)t * NH + h] = f2bf(acc[f][r]);
      }
    } else {
      int bb = m0 >> 11;
      int t0 = (m0 & 2047) + mr + hi * 4;
      short4 v;
      v.x = f2bf(acc[f][0]); v.y = f2bf(acc[f][1]);
      v.z = f2bf(acc[f][2]); v.w = f2bf(acc[f][3]);
      *(short4*)(VTo + ((size_t)(bb * 64 + h)) * NT + t0) = v;
    }
  }
}

// ---------------------------------------------------------------------------
// Kernel 2: FUSED flash attention with in-LDS combine. Grid = 512 blocks
// (b, qt of 32 q-rows), 8 waves. Wave w handles k-tiles {w, w+8, ...} (64 keys
// each) with private online softmax; one barrier; LDS weighted combine.
// Dispatch order pairs heavy (qt=63-i) with light (qt=i) per CU.
// ---------------------------------------------------------------------------
__global__ __launch_bounds__(512) void attn_fused(const short* __restrict__ Q,
                                                  const short* __restrict__ K,
                                                  const short* __restrict__ Vt,
                                                  float* __restrict__ out) {
  __shared__ short Pbuf[8][32][72];      // per-wave P transpose (36.9 KB)
  __shared__ short Osum[8][32][68];      // per-wave partial O, bf16 (34.8 KB)
  __shared__ float2 Ml[8][32];           // per-wave (m, l) per row (2 KB)

  const int tid = threadIdx.x;
  const int lane = tid & 63;
  const int wave = tid >> 6;             // 0..7
  const int l15 = lane & 15;
  const int hi = lane >> 4;
  const int kg = hi * 8;

  const int bid = blockIdx.x;
  const int half = bid >> 8;
  const int rr = bid & 255;
  const int b = rr >> 5;
  const int i = rr & 31;
  const int qt = (half == 0) ? (63 - i) : i;   // heavy first -> CU pairing
  const int ktmax = qt >> 1;
  const int q0 = qt * 32;

  // Q fragments: 32 rows x 64 h per block; wave-private copy
  bf16x8 qf[2][2];
#pragma unroll
  for (int m = 0; m < 2; ++m)
#pragma unroll
    for (int s = 0; s < 2; ++s)
      qf[m][s] = *(const bf16x8*)(Q + ((size_t)b * NT + q0 + m * 16 + l15) * NH +
                                  s * 32 + kg);

  f32x4 oacc[2][4];
#pragma unroll
  for (int m = 0; m < 2; ++m)
#pragma unroll
    for (int f = 0; f < 4; ++f) oacc[m][f] = (f32x4){0.f, 0.f, 0.f, 0.f};
  float m_[2][4], l_[2][4];
#pragma unroll
  for (int m = 0; m < 2; ++m)
#pragma unroll
    for (int r = 0; r < 4; ++r) { m_[m][r] = -INFINITY; l_[m][r] = 0.f; }

  for (int kt = wave; kt <= ktmax; kt += 8) {
    // K gather (B-frag of QK^T) and V^T gather (B-frag of PV)
    const short* kb = K + ((size_t)b * NT + kt * 64) * NH;
    bf16x8 kf[4][2], vf[4][2];
#pragma unroll
    for (int n = 0; n < 4; ++n)
#pragma unroll
      for (int s = 0; s < 2; ++s)
        kf[n][s] = *(const bf16x8*)(kb + (n * 16 + l15) * NH + s * 32 + kg);
#pragma unroll
    for (int f = 0; f < 4; ++f)
#pragma unroll
      for (int s = 0; s < 2; ++s)
        vf[f][s] = *(const bf16x8*)(Vt + ((size_t)(b * 64 + f * 16 + l15)) * NT +
                                    kt * 64 + s * 32 + kg);

    f32x4 S[2][4];
#pragma unroll
    for (int m = 0; m < 2; ++m)
#pragma unroll
      for (int n = 0; n < 4; ++n) {
        S[m][n] = (f32x4){0.f, 0.f, 0.f, 0.f};
        S[m][n] = MFMA(qf[m][0], kf[n][0], S[m][n]);
        S[m][n] = MFMA(qf[m][1], kf[n][1], S[m][n]);
      }
    if (kt == ktmax) {                   // causal mask (diagonal-crossing tile)
#pragma unroll
      for (int m = 0; m < 2; ++m)
#pragma unroll
        for (int n = 0; n < 4; ++n)
#pragma unroll
          for (int r = 0; r < 4; ++r)
            if (kt * 64 + n * 16 + l15 > q0 + m * 16 + hi * 4 + r)
              S[m][n][r] = -INFINITY;
    }
    // online softmax: 8 rows/lane at [m][r]; row's 64 keys over l15 x n
    float mt[2][4];
#pragma unroll
    for (int m = 0; m < 2; ++m)
#pragma unroll
      for (int r = 0; r < 4; ++r)
        mt[m][r] = fmaxf(fmaxf(S[m][0][r], S[m][1][r]),
                         fmaxf(S[m][2][r], S[m][3][r]));
#pragma unroll
    for (int d = 1; d < 16; d <<= 1)
#pragma unroll
      for (int m = 0; m < 2; ++m)
#pragma unroll
        for (int r = 0; r < 4; ++r) mt[m][r] = fmaxf(mt[m][r], __shfl_xor(mt[m][r], d));
    float alpha[2][4], rs[2][4];
#pragma unroll
    for (int m = 0; m < 2; ++m)
#pragma unroll
      for (int r = 0; r < 4; ++r) {
        float mn = fmaxf(m_[m][r], mt[m][r]);
        alpha[m][r] = __expf(m_[m][r] - mn);
        m_[m][r] = mn;
        rs[m][r] = 0.f;
      }
#pragma unroll
    for (int m = 0; m < 2; ++m)
#pragma unroll
      for (int n = 0; n < 4; ++n)
#pragma unroll
        for (int r = 0; r < 4; ++r) {
          float p = __expf(S[m][n][r] - m_[m][r]);
          S[m][n][r] = p;
          rs[m][r] += p;
        }
#pragma unroll
    for (int d = 1; d < 16; d <<= 1)
#pragma unroll
      for (int m = 0; m < 2; ++m)
#pragma unroll
        for (int r = 0; r < 4; ++r) rs[m][r] += __shfl_xor(rs[m][r], d);
#pragma unroll
    for (int m = 0; m < 2; ++m)
#pragma unroll
      for (int r = 0; r < 4; ++r) l_[m][r] = l_[m][r] * alpha[m][r] + rs[m][r];
#pragma unroll
    for (int m = 0; m < 2; ++m)
#pragma unroll
      for (int f = 0; f < 4; ++f)
#pragma unroll
        for (int r = 0; r < 4; ++r) oacc[m][f][r] *= alpha[m][r];

    // P transpose through per-wave LDS (wave-internal ordering, no barrier)
#pragma unroll
    for (int m = 0; m < 2; ++m)
#pragma unroll
      for (int n = 0; n < 4; ++n)
#pragma unroll
        for (int r = 0; r < 4; ++r)
          Pbuf[wave][m * 16 + hi * 4 + r][n * 16 + l15] = f2bf(S[m][n][r]);

    bf16x8 pa[2][2];
#pragma unroll
    for (int m = 0; m < 2; ++m)
#pragma unroll
      for (int s = 0; s < 2; ++s)
        pa[m][s] = *(const bf16x8*)&Pbuf[wave][m * 16 + l15][s * 32 + kg];
#pragma unroll
    for (int m = 0; m < 2; ++m)
#pragma unroll
      for (int f = 0; f < 4; ++f) {
        oacc[m][f] = MFMA(pa[m][0], vf[f][0], oacc[m][f]);
        oacc[m][f] = MFMA(pa[m][1], vf[f][1], oacc[m][f]);
      }
  }

  // publish per-wave results to LDS
  if (l15 == 0) {
#pragma unroll
    for (int m = 0; m < 2; ++m)
#pragma unroll
      for (int r = 0; r < 4; ++r)
        Ml[wave][m * 16 + hi * 4 + r] = make_float2(m_[m][r], l_[m][r]);
  }
#pragma unroll
  for (int m = 0; m < 2; ++m)
#pragma unroll
    for (int f = 0; f < 4; ++f)
#pragma unroll
      for (int r = 0; r < 4; ++r)
        Osum[wave][m * 16 + hi * 4 + r][f * 16 + l15] = f2bf(oacc[m][f][r]);
  __syncthreads();

  // combine: thread -> (row = tid>>4, cols c0..c0+3)
  {
    const int row = tid >> 4;
    const int c0 = (tid & 15) * 4;
    float M = -INFINITY;
#pragma unroll
    for (int w = 0; w < 8; ++w) M = fmaxf(M, Ml[w][row].x);
    float L = 0.f;
    float o[4] = {0.f, 0.f, 0.f, 0.f};
#pragma unroll
    for (int w = 0; w < 8; ++w) {
      float2 t = Ml[w][row];
      float wt = __expf(t.x - M);
      L += wt * t.y;
      short4 v = *(const short4*)&Osum[w][row][c0];
      o[0] += wt * bf2f(v.x); o[1] += wt * bf2f(v.y);
      o[2] += wt * bf2f(v.z); o[3] += wt * bf2f(v.w);
    }
    float inv = 1.f / L;
    float4 res = {o[0] * inv, o[1] * inv, o[2] * inv, o[3] * inv};
    *(float4*)(out + ((size_t)b * NT + q0 + row) * NH + c0) = res;
  }
}

// ---------------------------------------------------------------------------
extern "C" void kernel_launch(void* const* d_in, const int* in_sizes, int n_in,
                              void* d_out, int out_size, void* d_ws, size_t ws_size,
                              hipStream_t stream) {
  const float* x  = (const float*)d_in[0];
  const float* Wq = (const float*)d_in[1];
  const float* Wk = (const float*)d_in[2];
  const float* Wv = (const float*)d_in[3];
  float* out = (float*)d_out;

  char* ws = (char*)d_ws;
  short* Wt = (short*)ws;                          // 384 KB
  short* Qb = (short*)(ws + (size_t)(1 << 20));    // 2 MB
  short* Kb = (short*)(ws + (size_t)(3 << 20));    // 2 MB
  short* Vt = (short*)(ws + (size_t)(5 << 20));    // 2 MB (transposed V)

  hipLaunchKernelGGL(w_prep, dim3(48), dim3(256), 0, stream, Wq, Wk, Wv, Wt);
  hipLaunchKernelGGL(qkv_proj, dim3(512), dim3(256), 0, stream, x, Wt, Qb, Kb, Vt);
  hipLaunchKernelGGL(attn_fused, dim3(512), dim3(512), 0, stream, Qb, Kb, Vt, out);
}